// Round 7
// baseline (288.914 us; speedup 1.0000x reference)
//
#include <hip/hip_runtime.h>
#include <stdint.h>

// FourierPeriodNet: out[m][c] = sum_f sin(2pi t[m] f[f]) As[c][f] + cos(...) Ac[c][f]
// M = 262144, F = 128, C = 256.
// Round 10: 1KB-contiguous stores via LDS output transpose.
// Elimination chain: nt (R2, hurt), lgkm-barrier (R3, neutral), occupancy
// (R4, confounded), store spreading (R5, neutral), producer/consumer overlap
// (R6, neutral) -> write queues are full but drain at only ~3.5 TB/s vs
// fill's 6.5. Cause: D-fragment stores = 16 x 64B segments at 1KB stride per
// instruction (partial 128B lines, 16-way request fan-out). Fix: per 16-row
// stripe, all 4 waves stage acc into a 16x256 fp32 LDS tile (padded rows),
// lgkm-barrier, then each wave stores 4 complete rows, each row = one
// dwordx4 wave-instruction covering 1024 contiguous bytes (fill-like).
// MT=32 so LDS = 2x16.9K (features) + 2x16.6K (staging) = 67KB, 2 blocks/CU.

typedef __bf16 bf16x8 __attribute__((ext_vector_type(8)));
typedef float  floatx4 __attribute__((ext_vector_type(4)));

#define MT    32          // M rows per tile
#define F_    128         // frequencies
#define C_    256         // channels (N)
#define LSTR  264         // feature LDS row stride (bf16): 256 + 8 pad
#define SSTR  260         // staging LDS row stride (fp32): 256 + 4 pad
#define TPB   8           // tiles per block

// Orders LDS only: drain this wave's DS ops, then raw s_barrier. Global stores
// stay outstanding (write-only output, no in-kernel reader).
#define LDS_BARRIER() asm volatile("s_waitcnt lgkmcnt(0)\n\ts_barrier" ::: "memory")

__global__ __launch_bounds__(256, 2)
void fourier_fused(const float* __restrict__ t,
                   const float* __restrict__ freqs,
                   const float* __restrict__ amp_sin,
                   const float* __restrict__ amp_cos,
                   float* __restrict__ out)
{
    __shared__ __align__(16) __bf16 Af[2][MT * LSTR];   // 2 x 16896 B features
    __shared__ __align__(16) float  Sf[2][16 * SSTR];   // 2 x 16640 B out-stage

    const int tid  = threadIdx.x;
    const int wv   = tid >> 6;       // 0..3 -> 64-col slice of C
    const int lane = tid & 63;
    const int l15  = lane & 15;
    const int quad = lane >> 4;      // 0..3
    const int n0   = wv * 64;

    const int fgrp = tid & 15;       // which octet of 8 freqs (producer)
    const int rsub = tid >> 4;       // 0..15 (row-within-16, producer)

    const int tile0 = blockIdx.x * TPB;

    // ---- freqs ----
    const float4 f0v = *(const float4*)(freqs + fgrp * 8);
    const float4 f1v = *(const float4*)(freqs + fgrp * 8 + 4);
    const float fr[8] = {f0v.x, f0v.y, f0v.z, f0v.w, f1v.x, f1v.y, f1v.z, f1v.w};

    // ---- amp fragments (A-operand of swapped MFMA), held in VGPRs.
    // Lane (quad,l15) holds amp[n0 + ni*16 + l15][(ks&3)*32 + quad*8 + j];
    // ks<4 -> amp_sin (k=0..127), ks>=4 -> amp_cos (k=128..255).
    bf16x8 b[8][4];
    #pragma unroll
    for (int ks = 0; ks < 8; ++ks) {
        const float* __restrict__ amp = (ks < 4) ? amp_sin : amp_cos;
        const int f0 = (ks & 3) * 32 + quad * 8;
        #pragma unroll
        for (int ni = 0; ni < 4; ++ni) {
            const float* p = amp + (n0 + ni * 16 + l15) * F_ + f0;
            const float4 b0 = *(const float4*)(p);
            const float4 b1 = *(const float4*)(p + 4);
            b[ks][ni][0] = (__bf16)b0.x; b[ks][ni][1] = (__bf16)b0.y;
            b[ks][ni][2] = (__bf16)b0.z; b[ks][ni][3] = (__bf16)b0.w;
            b[ks][ni][4] = (__bf16)b1.x; b[ks][ni][5] = (__bf16)b1.y;
            b[ks][ni][6] = (__bf16)b1.z; b[ks][ni][7] = (__bf16)b1.w;
        }
    }

    // ---- prologue: produce tile0 into Af[0] ----
    float tprod[2];
    tprod[0] = t[tile0 * MT + rsub];
    tprod[1] = t[tile0 * MT + 16 + rsub];

    #pragma unroll
    for (int pass = 0; pass < 2; ++pass) {
        const float tval = tprod[pass];
        bf16x8 sv, cv;
        #pragma unroll
        for (int j = 0; j < 8; ++j) {
            // sin(2*pi*x) = v_sin(fract(x)): HW sin/cos take REVOLUTIONS
            const float r = __builtin_amdgcn_fractf(tval * fr[j]);
            sv[j] = (__bf16)__builtin_amdgcn_sinf(r);
            cv[j] = (__bf16)__builtin_amdgcn_cosf(r);
        }
        *(bf16x8*)&Af[0][(pass * 16 + rsub) * LSTR + fgrp * 8]      = sv;
        *(bf16x8*)&Af[0][(pass * 16 + rsub) * LSTR + F_ + fgrp * 8] = cv;
    }

    // t for tile1 (produced during it=0)
    tprod[0] = t[(tile0 + 1) * MT + rsub];
    tprod[1] = t[(tile0 + 1) * MT + 16 + rsub];

    LDS_BARRIER();

    for (int it = 0; it < TPB; ++it) {
        const int m0   = (tile0 + it) * MT;
        const int cur  = it & 1;
        const int nxt  = cur ^ 1;
        const bool prod = (it + 1 < TPB);

        // prefetch t for tile it+2
        float tnext[2];
        {
            const int mb = (it + 2 < TPB) ? (m0 + 2 * MT) : tile0 * MT;
            tnext[0] = t[mb + rsub];
            tnext[1] = t[mb + 16 + rsub];
        }

        #pragma unroll
        for (int mi = 0; mi < 2; ++mi) {
            // consumer A-frag reads issue first (latency under trans below)
            bf16x8 a[8];
            #pragma unroll
            for (int ks = 0; ks < 8; ++ks)
                a[ks] = *(const bf16x8*)
                    &Af[cur][(mi * 16 + l15) * LSTR + ks * 32 + quad * 8];

            // producer chunk: pass mi of tile it+1 -> Af[nxt]
            if (prod) {
                const float tval = tprod[mi];
                bf16x8 sv, cv;
                #pragma unroll
                for (int j = 0; j < 8; ++j) {
                    const float r = __builtin_amdgcn_fractf(tval * fr[j]);
                    sv[j] = (__bf16)__builtin_amdgcn_sinf(r);
                    cv[j] = (__bf16)__builtin_amdgcn_cosf(r);
                }
                *(bf16x8*)&Af[nxt][(mi * 16 + rsub) * LSTR + fgrp * 8]      = sv;
                *(bf16x8*)&Af[nxt][(mi * 16 + rsub) * LSTR + F_ + fgrp * 8] = cv;
            }

            // MFMA for stripe mi (K = 256), swapped operands:
            // D[ch = ni*16 + quad*4 + r][m = mi*16 + l15]
            floatx4 acc[4];
            #pragma unroll
            for (int ni = 0; ni < 4; ++ni)
                acc[ni] = (floatx4){0.f, 0.f, 0.f, 0.f};
            #pragma unroll
            for (int ks = 0; ks < 8; ++ks)
                #pragma unroll
                for (int ni = 0; ni < 4; ++ni)
                    acc[ni] = __builtin_amdgcn_mfma_f32_16x16x32_bf16(
                        b[ks][ni], a[ks], acc[ni], 0, 0, 0);

            // stage acc into Sf[mi]: row = m-row (l15), col = channel.
            // Write banks spread via SSTR=260 pad; 16B-aligned (quad*4 floats).
            #pragma unroll
            for (int ni = 0; ni < 4; ++ni)
                *(floatx4*)&Sf[mi][l15 * SSTR + n0 + ni * 16 + quad * 4] = acc[ni];

            LDS_BARRIER();
            // All 16 rows x 256 ch of stripe mi now complete in Sf[mi].
            // (Staging reuse next tile is safe: each wave's reads below are
            // drained by its lgkmcnt(0) at the NEXT stripe barrier, which all
            // waves pass before any re-writes Sf[mi].)

            // each wave stores 4 complete rows; one dwordx4 instruction
            // covers 64 lanes x 16B = 1024 contiguous bytes = one out row.
            #pragma unroll
            for (int rr = 0; rr < 4; ++rr) {
                const int row = wv * 4 + rr;
                const floatx4 v = *(const floatx4*)&Sf[mi][row * SSTR + lane * 4];
                *(floatx4*)(out + (size_t)(m0 + mi * 16 + row) * C_ + lane * 4) = v;
            }
        }

        tprod[0] = tnext[0];
        tprod[1] = tnext[1];
    }
}

extern "C" void kernel_launch(void* const* d_in, const int* in_sizes, int n_in,
                              void* d_out, int out_size, void* d_ws, size_t ws_size,
                              hipStream_t stream) {
    const float* t   = (const float*)d_in[0];
    const float* fq  = (const float*)d_in[1];
    const float* As  = (const float*)d_in[2];
    const float* Ac  = (const float*)d_in[3];
    float* outp      = (float*)d_out;

    const int M = in_sizes[0];               // 262144
    hipLaunchKernelGGL(fourier_fused, dim3(M / (MT * TPB)), dim3(256), 0, stream,
                       t, fq, As, Ac, outp);
}